// Round 1
// baseline (1604.088 us; speedup 1.0000x reference)
//
#include <hip/hip_runtime.h>
#include <hip/hip_bf16.h>

#define D 128
#define GR 64   // rows per GEMM block

// ---------- transpose 128x128 (weights, once per launch) ----------
__global__ void k_transpose(const float* __restrict__ src, float* __restrict__ dst) {
  int m = blockIdx.y;
  const float* s = src + (size_t)m * D * D;
  float* d = dst + (size_t)m * D * D;
  int idx = blockIdx.x * blockDim.x + threadIdx.x;
  if (idx < D * D) {
    int r = idx >> 7, c = idx & (D - 1);
    d[c * D + r] = s[idx];
  }
}

// ---------- CSR build ----------
__global__ void k_hist(const int* __restrict__ dstI, int* __restrict__ cnt, int E) {
  int e = blockIdx.x * blockDim.x + threadIdx.x;
  if (e < E) atomicAdd(&cnt[dstI[e]], 1);
}

__global__ void k_scan1(const int* __restrict__ cnt, int* __restrict__ off,
                        int* __restrict__ bsum, int n) {
  __shared__ int sd[256];
  int t = threadIdx.x;
  int i = blockIdx.x * 256 + t;
  int x = (i < n) ? cnt[i] : 0;
  sd[t] = x;
  __syncthreads();
  for (int s = 1; s < 256; s <<= 1) {
    int v = (t >= s) ? sd[t - s] : 0;
    __syncthreads();
    sd[t] += v;
    __syncthreads();
  }
  if (i < n) off[i] = sd[t] - x;
  if (t == 255) bsum[blockIdx.x] = sd[255];
}

__global__ void k_scan2(const int* __restrict__ bsum, int* __restrict__ boff, int nb) {
  __shared__ int sd[256];
  int t = threadIdx.x;
  int x = (t < nb) ? bsum[t] : 0;
  sd[t] = x;
  __syncthreads();
  for (int s = 1; s < 256; s <<= 1) {
    int v = (t >= s) ? sd[t - s] : 0;
    __syncthreads();
    sd[t] += v;
    __syncthreads();
  }
  if (t < nb) boff[t] = sd[t] - x;
}

__global__ void k_scan3(int* __restrict__ off, const int* __restrict__ boff,
                        int* __restrict__ cursor, int n) {
  int i = blockIdx.x * blockDim.x + threadIdx.x;
  if (i < n) {
    int v = off[i] + boff[i >> 8];
    off[i] = v;
    cursor[i] = v;
  }
}

__global__ void k_fill(const int* __restrict__ srcI, const int* __restrict__ dstI,
                       int* __restrict__ cursor, int* __restrict__ eidx, int E) {
  int e = blockIdx.x * blockDim.x + threadIdx.x;
  if (e < E) {
    int p = atomicAdd(&cursor[dstI[e]], 1);
    eidx[p] = srcI[e];
  }
}

// ---------- neighbor-mean aggregation: one wave per node ----------
__global__ void k_aggregate(const float* __restrict__ h, const int* __restrict__ off,
                            const int* __restrict__ eidx, float* __restrict__ agg,
                            int N, int E) {
  int wid = (int)((blockIdx.x * (size_t)blockDim.x + threadIdx.x) >> 6);
  int lane = threadIdx.x & 63;
  if (wid >= N) return;
  int start = off[wid];
  int end = (wid == N - 1) ? E : off[wid + 1];
  float2 acc = make_float2(0.f, 0.f);
  const int c = lane * 2;
  for (int e = start; e < end; ++e) {
    int s = eidx[e];
    float2 v = *(const float2*)&h[(size_t)s * D + c];
    acc.x += v.x;
    acc.y += v.y;
  }
  float inv = (end > start) ? 1.0f / (float)(end - start) : 0.0f;
  acc.x *= inv;
  acc.y *= inv;
  *(float2*)&agg[(size_t)wid * D + c] = acc;
}

// ---------- GEMM: out[i][j] = sum_k A1[i][k]*W1T[k][j] (+ A2*W2T) + bias[j], opt *mask[i] ----------
template <bool DUAL, bool MASK>
__global__ void k_gemm(const float* __restrict__ A1, const float* __restrict__ W1T,
                       const float* __restrict__ bias,
                       const float* __restrict__ A2, const float* __restrict__ W2T,
                       const float* __restrict__ mask, float* __restrict__ out, int N) {
  extern __shared__ float smem[];
  float* a1s = smem;                 // [GR][D]
  float* a2s = smem + GR * D;        // [GR][D] if DUAL
  int t = threadIdx.x;
  int r0 = blockIdx.x * GR;
  // stage tiles (coalesced float4)
  #pragma unroll
  for (int i = 0; i < (GR * D / 4) / 256; ++i) {
    int f = t + i * 256;
    int r = f >> 5, c4 = f & 31;
    int gr = r0 + r;
    float4 v = (gr < N) ? *(const float4*)&A1[(size_t)gr * D + c4 * 4]
                        : make_float4(0, 0, 0, 0);
    *(float4*)&a1s[r * D + c4 * 4] = v;
    if (DUAL) {
      float4 u = (gr < N) ? *(const float4*)&A2[(size_t)gr * D + c4 * 4]
                          : make_float4(0, 0, 0, 0);
      *(float4*)&a2s[r * D + c4 * 4] = u;
    }
  }
  __syncthreads();

  int j0 = (t & 31) * 4;      // 4 consecutive output cols
  int rr = (t >> 5) * 8;      // 8 rows
  float4 acc[8];
  #pragma unroll
  for (int r = 0; r < 8; ++r) acc[r] = make_float4(0, 0, 0, 0);

  #pragma unroll 2
  for (int k = 0; k < D; k += 4) {
    float4 w0 = *(const float4*)&W1T[(k + 0) * D + j0];
    float4 w1 = *(const float4*)&W1T[(k + 1) * D + j0];
    float4 w2 = *(const float4*)&W1T[(k + 2) * D + j0];
    float4 w3 = *(const float4*)&W1T[(k + 3) * D + j0];
    #pragma unroll
    for (int r = 0; r < 8; ++r) {
      float4 av = *(const float4*)&a1s[(rr + r) * D + k];
      acc[r].x += av.x * w0.x + av.y * w1.x + av.z * w2.x + av.w * w3.x;
      acc[r].y += av.x * w0.y + av.y * w1.y + av.z * w2.y + av.w * w3.y;
      acc[r].z += av.x * w0.z + av.y * w1.z + av.z * w2.z + av.w * w3.z;
      acc[r].w += av.x * w0.w + av.y * w1.w + av.z * w2.w + av.w * w3.w;
    }
    if (DUAL) {
      float4 u0 = *(const float4*)&W2T[(k + 0) * D + j0];
      float4 u1 = *(const float4*)&W2T[(k + 1) * D + j0];
      float4 u2 = *(const float4*)&W2T[(k + 2) * D + j0];
      float4 u3 = *(const float4*)&W2T[(k + 3) * D + j0];
      #pragma unroll
      for (int r = 0; r < 8; ++r) {
        float4 av = *(const float4*)&a2s[(rr + r) * D + k];
        acc[r].x += av.x * u0.x + av.y * u1.x + av.z * u2.x + av.w * u3.x;
        acc[r].y += av.x * u0.y + av.y * u1.y + av.z * u2.y + av.w * u3.y;
        acc[r].z += av.x * u0.z + av.y * u1.z + av.z * u2.z + av.w * u3.z;
        acc[r].w += av.x * u0.w + av.y * u1.w + av.z * u2.w + av.w * u3.w;
      }
    }
  }

  float4 b4 = *(const float4*)&bias[j0];
  #pragma unroll
  for (int r = 0; r < 8; ++r) {
    int gr = r0 + rr + r;
    if (gr < N) {
      float4 v;
      v.x = acc[r].x + b4.x;
      v.y = acc[r].y + b4.y;
      v.z = acc[r].z + b4.z;
      v.w = acc[r].w + b4.w;
      if (MASK) {
        float m = mask[gr];
        v.x *= m; v.y *= m; v.z *= m; v.w *= m;
      }
      *(float4*)&out[(size_t)gr * D + j0] = v;
    }
  }
}

// ---------- column stats (sum, sumsq) ----------
__global__ void k_colstats(const float* __restrict__ m, float* __restrict__ sums, int N) {
  int j = threadIdx.x;  // 128 threads
  float s = 0.f, s2 = 0.f;
  for (int i = blockIdx.x; i < N; i += gridDim.x) {
    float v = m[(size_t)i * D + j];
    s += v;
    s2 += v * v;
  }
  atomicAdd(&sums[j], s);
  atomicAdd(&sums[D + j], s2);
}

// ---------- BN (stats finalized in-kernel) + ReLU, in place ----------
__global__ void k_bnrelu(float* __restrict__ m, const float* __restrict__ sums,
                         const float* __restrict__ gamma, const float* __restrict__ beta,
                         int N, float invN) {
  int f4 = blockIdx.x * blockDim.x + threadIdx.x;
  if (f4 >= N * (D / 4)) return;
  int j0 = (f4 & 31) * 4;
  float4 v = ((const float4*)m)[f4];
  float4 s  = *(const float4*)&sums[j0];
  float4 s2 = *(const float4*)&sums[D + j0];
  float4 g = *(const float4*)&gamma[j0];
  float4 b = *(const float4*)&beta[j0];
  float mu, var, sc, sh;
  mu = s.x * invN;  var = fmaxf(s2.x * invN - mu * mu, 0.f);
  sc = g.x * rsqrtf(var + 1e-5f); sh = b.x - mu * sc;
  v.x = fmaxf(v.x * sc + sh, 0.f);
  mu = s.y * invN;  var = fmaxf(s2.y * invN - mu * mu, 0.f);
  sc = g.y * rsqrtf(var + 1e-5f); sh = b.y - mu * sc;
  v.y = fmaxf(v.y * sc + sh, 0.f);
  mu = s.z * invN;  var = fmaxf(s2.z * invN - mu * mu, 0.f);
  sc = g.z * rsqrtf(var + 1e-5f); sh = b.z - mu * sc;
  v.z = fmaxf(v.z * sc + sh, 0.f);
  mu = s.w * invN;  var = fmaxf(s2.w * invN - mu * mu, 0.f);
  sc = g.w * rsqrtf(var + 1e-5f); sh = b.w - mu * sc;
  v.w = fmaxf(v.w * sc + sh, 0.f);
  ((float4*)m)[f4] = v;
}

// ---------- state gather ----------
__global__ void k_gather(const float* __restrict__ h, const int* __restrict__ uidx,
                         float* __restrict__ outp, int U) {
  int u = blockIdx.x;
  int t = threadIdx.x;  // 32 threads
  int s = uidx[u];
  *(float4*)&outp[(size_t)u * D + t * 4] = *(const float4*)&h[(size_t)s * D + t * 4];
}

extern "C" void kernel_launch(void* const* d_in, const int* in_sizes, int n_in,
                              void* d_out, int out_size, void* d_ws, size_t ws_size,
                              hipStream_t stream) {
  const float* x        = (const float*)d_in[0];
  const int*   edge     = (const int*)d_in[1];
  const float* amask    = (const float*)d_in[2];
  const int*   uindex   = (const int*)d_in[3];
  const float* lin_l_w  = (const float*)d_in[4];
  const float* lin_l_b  = (const float*)d_in[5];
  const float* lin_r_w  = (const float*)d_in[6];
  const float* bn_gamma = (const float*)d_in[7];
  const float* bn_beta  = (const float*)d_in[8];
  const float* ro_w1    = (const float*)d_in[9];
  const float* ro_b1    = (const float*)d_in[10];
  const float* ro_bng   = (const float*)d_in[11];
  const float* ro_bnb   = (const float*)d_in[12];
  const float* ro_w2    = (const float*)d_in[13];
  const float* ro_b2    = (const float*)d_in[14];

  const int N = in_sizes[0] / D;
  const int E = in_sizes[1] / 2;
  const int U = in_sizes[3];
  const int L = in_sizes[4] / (D * D);

  const int* srcI = edge;
  const int* dstI = edge + E;

  float* outH     = (float*)d_out;               // [N][D]
  float* outAtom  = outH + (size_t)N * D;        // [N][D]
  float* outState = outAtom + (size_t)N * D;     // [U][D]

  // workspace carve (agg lives in the atom output region until the final GEMM)
  char* w = (char*)d_ws;
  float* hA = (float*)w;   w += (size_t)N * D * 4;
  float* hB = (float*)w;   w += (size_t)N * D * 4;
  float* WT = (float*)w;   w += (size_t)(2 * L + 2) * D * D * 4;
  float* sums = (float*)w; w += 2 * D * 4;
  int* off = (int*)w;      w += (size_t)(N + 1) * 4;
  int* cursor = (int*)w;   w += (size_t)N * 4;
  int* bsum = (int*)w;     w += 1024;
  int* boff = (int*)w;     w += 1024;
  int* eidx = (int*)w;     w += (size_t)E * 4;
  float* agg = outAtom;

  float* WlT = WT;
  float* WrT = WlT + (size_t)L * D * D;
  float* w1T = WrT + (size_t)L * D * D;
  float* w2T = w1T + D * D;

  // 1) transpose weights
  k_transpose<<<dim3(64, L), 256, 0, stream>>>(lin_l_w, WlT);
  k_transpose<<<dim3(64, L), 256, 0, stream>>>(lin_r_w, WrT);
  k_transpose<<<dim3(64, 1), 256, 0, stream>>>(ro_w1, w1T);
  k_transpose<<<dim3(64, 1), 256, 0, stream>>>(ro_w2, w2T);

  // 2) CSR build (cursor doubles as cnt for the histogram)
  hipMemsetAsync(cursor, 0, (size_t)N * 4, stream);
  int nbE = (E + 255) / 256;
  int nbN = (N + 255) / 256;
  k_hist<<<nbE, 256, 0, stream>>>(dstI, cursor, E);
  k_scan1<<<nbN, 256, 0, stream>>>(cursor, off, bsum, N);
  k_scan2<<<1, 256, 0, stream>>>(bsum, boff, nbN);
  k_scan3<<<nbN, 256, 0, stream>>>(off, boff, cursor, N);
  k_fill<<<nbE, 256, 0, stream>>>(srcI, dstI, cursor, eidx, E);

  int gemmBlocks = (N + GR - 1) / GR;
  int aggBlocks = (N + 3) / 4;
  int bnBlocks = (int)(((size_t)N * (D / 4) + 255) / 256);
  float invN = 1.0f / (float)N;

  // 3) layers
  const float* hin = x;
  for (int l = 0; l < L; ++l) {
    float* hout = (l == L - 1) ? outH : ((l == 0) ? hA : hB);
    k_aggregate<<<aggBlocks, 256, 0, stream>>>(hin, off, eidx, agg, N, E);
    k_gemm<true, false><<<gemmBlocks, 256, 2 * GR * D * 4, stream>>>(
        agg, WlT + (size_t)l * D * D, lin_l_b + (size_t)l * D,
        hin, WrT + (size_t)l * D * D, nullptr, hout, N);
    hipMemsetAsync(sums, 0, 2 * D * 4, stream);
    k_colstats<<<512, 128, 0, stream>>>(hout, sums, N);
    k_bnrelu<<<bnBlocks, 256, 0, stream>>>(hout, sums, bn_gamma + (size_t)l * D,
                                           bn_beta + (size_t)l * D, N, invN);
    hin = hout;
  }

  // 4) readout
  float* z = hA;
  k_gemm<false, false><<<gemmBlocks, 256, GR * D * 4, stream>>>(
      outH, w1T, ro_b1, nullptr, nullptr, nullptr, z, N);
  hipMemsetAsync(sums, 0, 2 * D * 4, stream);
  k_colstats<<<512, 128, 0, stream>>>(z, sums, N);
  k_bnrelu<<<bnBlocks, 256, 0, stream>>>(z, sums, ro_bng, ro_bnb, N, invN);
  k_gemm<false, true><<<gemmBlocks, 256, GR * D * 4, stream>>>(
      z, w2T, ro_b2, nullptr, nullptr, amask, outAtom, N);
  k_gather<<<U, 32, 0, stream>>>(outH, uindex, outState, U);
}

// Round 2
// 524.610 us; speedup vs baseline: 3.0577x; 3.0577x over previous
//
#include <hip/hip_runtime.h>

#define D 128

typedef __attribute__((ext_vector_type(8))) short bf16x8;
typedef __attribute__((ext_vector_type(4))) float f32x4;

__device__ __forceinline__ ushort f2b(float f) {
  union { float f; unsigned u; } a; a.f = f;
  unsigned u = a.u;
  return (ushort)((u + 0x7fffu + ((u >> 16) & 1u)) >> 16);  // RNE
}
__device__ __forceinline__ float b2f_lo(unsigned v) {
  union { unsigned u; float f; } a; a.u = v << 16; return a.f;
}
__device__ __forceinline__ float b2f_hi(unsigned v) {
  union { unsigned u; float f; } a; a.u = v & 0xffff0000u; return a.f;
}

// ---------- fp32 -> bf16 casts ----------
__global__ void k_cast(const float* __restrict__ s, ushort* __restrict__ d, int n) {
  int i = blockIdx.x * blockDim.x + threadIdx.x;
  if (i < n) d[i] = f2b(s[i]);
}
__global__ void k_cast_pad(const float* __restrict__ s, ushort* __restrict__ d, int n, int np) {
  int i = blockIdx.x * blockDim.x + threadIdx.x;
  if (i < np) d[i] = (i < n) ? f2b(s[i]) : (ushort)0;
}

// ---------- CSR build ----------
__global__ void k_hist(const int* __restrict__ dstI, int* __restrict__ cnt, int E) {
  int e = blockIdx.x * blockDim.x + threadIdx.x;
  if (e < E) atomicAdd(&cnt[dstI[e]], 1);
}
__global__ void k_scan1(const int* __restrict__ cnt, int* __restrict__ off,
                        int* __restrict__ bsum, int n) {
  __shared__ int sd[256];
  int t = threadIdx.x;
  int i = blockIdx.x * 256 + t;
  int x = (i < n) ? cnt[i] : 0;
  sd[t] = x;
  __syncthreads();
  for (int s = 1; s < 256; s <<= 1) {
    int v = (t >= s) ? sd[t - s] : 0;
    __syncthreads();
    sd[t] += v;
    __syncthreads();
  }
  if (i < n) off[i] = sd[t] - x;
  if (t == 255) bsum[blockIdx.x] = sd[255];
}
__global__ void k_scan2(const int* __restrict__ bsum, int* __restrict__ boff, int nb) {
  __shared__ int sd[256];
  int t = threadIdx.x;
  int x = (t < nb) ? bsum[t] : 0;
  sd[t] = x;
  __syncthreads();
  for (int s = 1; s < 256; s <<= 1) {
    int v = (t >= s) ? sd[t - s] : 0;
    __syncthreads();
    sd[t] += v;
    __syncthreads();
  }
  if (t < nb) boff[t] = sd[t] - x;
}
__global__ void k_scan3(int* __restrict__ off, const int* __restrict__ boff,
                        int* __restrict__ cursor, int n) {
  int i = blockIdx.x * blockDim.x + threadIdx.x;
  if (i < n) {
    int v = off[i] + boff[i >> 8];
    off[i] = v;
    cursor[i] = v;
  }
}
__global__ void k_fill(const int* __restrict__ srcI, const int* __restrict__ dstI,
                       int* __restrict__ cursor, int* __restrict__ eidx, int E) {
  int e = blockIdx.x * blockDim.x + threadIdx.x;
  if (e < E) {
    int p = atomicAdd(&cursor[dstI[e]], 1);
    eidx[p] = srcI[e];
  }
}

// ---------- neighbor-mean aggregation (bf16 in/out, fp32 accum): one wave per node ----------
__global__ void k_agg(const ushort* __restrict__ hb, const int* __restrict__ off,
                      const int* __restrict__ eidx, ushort* __restrict__ aggb,
                      int N, int Np, int E) {
  int wid = (int)((blockIdx.x * (size_t)blockDim.x + threadIdx.x) >> 6);
  int lane = threadIdx.x & 63;
  if (wid >= Np) return;
  unsigned* dst = (unsigned*)&aggb[(size_t)wid * D] + lane;
  if (wid >= N) { *dst = 0u; return; }
  int start = off[wid];
  int end = (wid == N - 1) ? E : off[wid + 1];
  float ax = 0.f, ay = 0.f;
  for (int e = start; e < end; ++e) {
    int s = eidx[e];
    unsigned v = *((const unsigned*)&hb[(size_t)s * D] + lane);
    ax += b2f_lo(v);
    ay += b2f_hi(v);
  }
  float inv = (end > start) ? 1.0f / (float)(end - start) : 0.0f;
  *dst = (unsigned)f2b(ax * inv) | ((unsigned)f2b(ay * inv) << 16);
}

// ---------- MFMA GEMM: out[i][j] = sum_k A1[i][k]*W1[j][k] (+ A2[i][k]*W2[j][k]) + bias[j]
// block = 128 rows x 128 cols, 4 waves (2x2), wave = 64x64, mfma_f32_16x16x32_bf16.
// A row-fragment: row = lane&15, k = (lane>>4)*8..+8 (contiguous 16B).
// B (=W) fragment: col (W row) = lane&15, same k slice (contiguous 16B) -> no transpose needed.
// C/D: col = lane&15, row = (lane>>4)*4 + reg.
// STATS: fused column sum/sumsq (over the final biased values) into sums[0..127]/sums[128..255].
template <bool DUAL, bool MASK, bool STATS>
__global__ __launch_bounds__(256) void k_mm(
    const ushort* __restrict__ A1, const ushort* __restrict__ W1,
    const float* __restrict__ bias,
    const ushort* __restrict__ A2, const ushort* __restrict__ W2,
    const float* __restrict__ mask,
    float* __restrict__ out, float* __restrict__ sums, int N) {
  __shared__ float ls[2 * D];
  int t = threadIdx.x;
  int lane = t & 63;
  int wid = t >> 6;
  int wr = wid >> 1, wc = wid & 1;
  int r0 = blockIdx.x * 128 + wr * 64;
  int c0 = wc * 64;
  int lr = lane & 15;
  int lk = (lane >> 4) * 8;

  f32x4 acc[4][4];
#pragma unroll
  for (int i = 0; i < 4; ++i)
#pragma unroll
    for (int j = 0; j < 4; ++j) acc[i][j] = (f32x4){0.f, 0.f, 0.f, 0.f};

#pragma unroll
  for (int ks = 0; ks < 4; ++ks) {
    int kb = ks * 32 + lk;
    bf16x8 a1[4], a2[4];
#pragma unroll
    for (int rt = 0; rt < 4; ++rt) {
      a1[rt] = *(const bf16x8*)&A1[(size_t)(r0 + rt * 16 + lr) * D + kb];
      if (DUAL) a2[rt] = *(const bf16x8*)&A2[(size_t)(r0 + rt * 16 + lr) * D + kb];
    }
#pragma unroll
    for (int jt = 0; jt < 4; ++jt) {
      bf16x8 b1 = *(const bf16x8*)&W1[(size_t)(c0 + jt * 16 + lr) * D + kb];
#pragma unroll
      for (int rt = 0; rt < 4; ++rt)
        acc[rt][jt] = __builtin_amdgcn_mfma_f32_16x16x32_bf16(a1[rt], b1, acc[rt][jt], 0, 0, 0);
      if (DUAL) {
        bf16x8 b2 = *(const bf16x8*)&W2[(size_t)(c0 + jt * 16 + lr) * D + kb];
#pragma unroll
        for (int rt = 0; rt < 4; ++rt)
          acc[rt][jt] = __builtin_amdgcn_mfma_f32_16x16x32_bf16(a2[rt], b2, acc[rt][jt], 0, 0, 0);
      }
    }
  }

  if (STATS) {
    if (t < 2 * D) ls[t] = 0.f;
    __syncthreads();
  }

  int crow = (lane >> 4) * 4;
  float s1v[4], s2v[4];
#pragma unroll
  for (int jt = 0; jt < 4; ++jt) { s1v[jt] = 0.f; s2v[jt] = 0.f; }

#pragma unroll
  for (int rt = 0; rt < 4; ++rt) {
    int rbase = r0 + rt * 16 + crow;
#pragma unroll
    for (int jt = 0; jt < 4; ++jt) {
      int col = c0 + jt * 16 + lr;
      float bv = bias[col];
#pragma unroll
      for (int rg = 0; rg < 4; ++rg) {
        int row = rbase + rg;
        if (row < N) {
          float v = acc[rt][jt][rg] + bv;
          if (MASK) v *= mask[row];
          out[(size_t)row * D + col] = v;
          if (STATS) { s1v[jt] += v; s2v[jt] += v * v; }
        }
      }
    }
  }

  if (STATS) {
#pragma unroll
    for (int jt = 0; jt < 4; ++jt) {
      float a = s1v[jt], b = s2v[jt];
      a += __shfl_xor(a, 16, 64); a += __shfl_xor(a, 32, 64);
      b += __shfl_xor(b, 16, 64); b += __shfl_xor(b, 32, 64);
      if (lane < 16) {
        int col = c0 + jt * 16 + lane;
        atomicAdd(&ls[col], a);
        atomicAdd(&ls[D + col], b);
      }
    }
    __syncthreads();
    if (t < 2 * D) atomicAdd(&sums[t], ls[t]);
  }
}

// ---------- BN + ReLU; writes bf16 next-activation (padded) and optionally fp32 ----------
template <bool F32OUT>
__global__ void k_bnrelu(const float* __restrict__ pre, const float* __restrict__ sums,
                         const float* __restrict__ gamma, const float* __restrict__ beta,
                         float* __restrict__ fout, ushort* __restrict__ bout,
                         int N, int Np, float invN) {
  int i4 = blockIdx.x * blockDim.x + threadIdx.x;
  if (i4 >= Np * (D / 4)) return;
  int row = i4 >> 5;
  int c4 = (i4 & 31) * 4;
  union { ushort us[4]; uint2 u2; } pk;
  if (row < N) {
    float4 v = *(const float4*)&pre[(size_t)row * D + c4];
    float4 s = *(const float4*)&sums[c4];
    float4 q = *(const float4*)&sums[D + c4];
    float4 g = *(const float4*)&gamma[c4];
    float4 b = *(const float4*)&beta[c4];
    float mu, var, sc, sh;
    mu = s.x * invN; var = fmaxf(q.x * invN - mu * mu, 0.f);
    sc = g.x * rsqrtf(var + 1e-5f); sh = b.x - mu * sc;
    v.x = fmaxf(fmaf(v.x, sc, sh), 0.f);
    mu = s.y * invN; var = fmaxf(q.y * invN - mu * mu, 0.f);
    sc = g.y * rsqrtf(var + 1e-5f); sh = b.y - mu * sc;
    v.y = fmaxf(fmaf(v.y, sc, sh), 0.f);
    mu = s.z * invN; var = fmaxf(q.z * invN - mu * mu, 0.f);
    sc = g.z * rsqrtf(var + 1e-5f); sh = b.z - mu * sc;
    v.z = fmaxf(fmaf(v.z, sc, sh), 0.f);
    mu = s.w * invN; var = fmaxf(q.w * invN - mu * mu, 0.f);
    sc = g.w * rsqrtf(var + 1e-5f); sh = b.w - mu * sc;
    v.w = fmaxf(fmaf(v.w, sc, sh), 0.f);
    if (F32OUT) *(float4*)&fout[(size_t)row * D + c4] = v;
    pk.us[0] = f2b(v.x); pk.us[1] = f2b(v.y);
    pk.us[2] = f2b(v.z); pk.us[3] = f2b(v.w);
  } else {
    pk.u2 = make_uint2(0u, 0u);
  }
  *(uint2*)&bout[(size_t)row * D + c4] = pk.u2;
}

// ---------- state gather ----------
__global__ void k_gather(const float* __restrict__ h, const int* __restrict__ uidx,
                         float* __restrict__ outp, int U) {
  int u = blockIdx.x;
  int t = threadIdx.x;  // 32 threads
  int s = uidx[u];
  *(float4*)&outp[(size_t)u * D + t * 4] = *(const float4*)&h[(size_t)s * D + t * 4];
}

extern "C" void kernel_launch(void* const* d_in, const int* in_sizes, int n_in,
                              void* d_out, int out_size, void* d_ws, size_t ws_size,
                              hipStream_t stream) {
  const float* x        = (const float*)d_in[0];
  const int*   edge     = (const int*)d_in[1];
  const float* amask    = (const float*)d_in[2];
  const int*   uindex   = (const int*)d_in[3];
  const float* lin_l_w  = (const float*)d_in[4];
  const float* lin_l_b  = (const float*)d_in[5];
  const float* lin_r_w  = (const float*)d_in[6];
  const float* bn_gamma = (const float*)d_in[7];
  const float* bn_beta  = (const float*)d_in[8];
  const float* ro_w1    = (const float*)d_in[9];
  const float* ro_b1    = (const float*)d_in[10];
  const float* ro_bng   = (const float*)d_in[11];
  const float* ro_bnb   = (const float*)d_in[12];
  const float* ro_w2    = (const float*)d_in[13];
  const float* ro_b2    = (const float*)d_in[14];

  const int N = in_sizes[0] / D;
  const int E = in_sizes[1] / 2;
  const int U = in_sizes[3];
  const int L = in_sizes[4] / (D * D);
  const int Np = ((N + 127) / 128) * 128;

  const int* srcI = edge;
  const int* dstI = edge + E;

  float* outH     = (float*)d_out;               // [N][D]
  float* outAtom  = outH + (size_t)N * D;        // [N][D]
  float* outState = outAtom + (size_t)N * D;     // [U][D]

  // workspace carve
  char* w = (char*)d_ws;
  ushort* hb   = (ushort*)w; w += (size_t)Np * D * 2;
  ushort* aggb = (ushort*)w; w += (size_t)Np * D * 2;
  float*  pre  = (float*)w;  w += (size_t)Np * D * 4;
  ushort* wlb  = (ushort*)w; w += (size_t)L * D * D * 2;
  ushort* wrb  = (ushort*)w; w += (size_t)L * D * D * 2;
  ushort* w1b  = (ushort*)w; w += (size_t)D * D * 2;
  ushort* w2b  = (ushort*)w; w += (size_t)D * D * 2;
  float*  sums = (float*)w;  w += 2 * D * 4;
  int* off    = (int*)w;     w += (size_t)(N + 1) * 4;
  int* cursor = (int*)w;     w += (size_t)N * 4;
  int* bsum   = (int*)w;     w += 1024;
  int* boff   = (int*)w;     w += 1024;
  int* eidx   = (int*)w;     w += (size_t)E * 4;

  // 1) casts
  k_cast_pad<<<(Np * D / 4 + 255) / 256 * 4, 256, 0, stream>>>(x, hb, N * D, Np * D);
  k_cast<<<(L * D * D + 255) / 256, 256, 0, stream>>>(lin_l_w, wlb, L * D * D);
  k_cast<<<(L * D * D + 255) / 256, 256, 0, stream>>>(lin_r_w, wrb, L * D * D);
  k_cast<<<(D * D + 255) / 256, 256, 0, stream>>>(ro_w1, w1b, D * D);
  k_cast<<<(D * D + 255) / 256, 256, 0, stream>>>(ro_w2, w2b, D * D);

  // 2) CSR build (cursor doubles as cnt)
  hipMemsetAsync(cursor, 0, (size_t)N * 4, stream);
  int nbE = (E + 255) / 256;
  int nbN = (N + 255) / 256;
  k_hist<<<nbE, 256, 0, stream>>>(dstI, cursor, E);
  k_scan1<<<nbN, 256, 0, stream>>>(cursor, off, bsum, N);
  k_scan2<<<1, 256, 0, stream>>>(bsum, boff, nbN);
  k_scan3<<<nbN, 256, 0, stream>>>(off, boff, cursor, N);
  k_fill<<<nbE, 256, 0, stream>>>(srcI, dstI, cursor, eidx, E);

  const int mmBlocks = Np / 128;
  const int aggBlocks = (Np + 3) / 4;            // 4 waves (nodes) per 256-thr block
  const int bnBlocks = (Np * (D / 4) + 255) / 256;
  const float invN = 1.0f / (float)N;

  // 3) layers
  for (int l = 0; l < L; ++l) {
    k_agg<<<aggBlocks, 256, 0, stream>>>(hb, off, eidx, aggb, N, Np, E);
    hipMemsetAsync(sums, 0, 2 * D * 4, stream);
    k_mm<true, false, true><<<mmBlocks, 256, 0, stream>>>(
        aggb, wlb + (size_t)l * D * D, lin_l_b + (size_t)l * D,
        hb, wrb + (size_t)l * D * D, nullptr, pre, sums, N);
    if (l == L - 1)
      k_bnrelu<true><<<bnBlocks, 256, 0, stream>>>(pre, sums, bn_gamma + (size_t)l * D,
                                                   bn_beta + (size_t)l * D, outH, hb, N, Np, invN);
    else
      k_bnrelu<false><<<bnBlocks, 256, 0, stream>>>(pre, sums, bn_gamma + (size_t)l * D,
                                                    bn_beta + (size_t)l * D, nullptr, hb, N, Np, invN);
  }

  // 4) readout
  hipMemsetAsync(sums, 0, 2 * D * 4, stream);
  k_mm<false, false, true><<<mmBlocks, 256, 0, stream>>>(
      hb, w1b, ro_b1, nullptr, nullptr, nullptr, pre, sums, N);
  k_bnrelu<false><<<bnBlocks, 256, 0, stream>>>(pre, sums, ro_bng, ro_bnb, nullptr, aggb, N, Np, invN);
  k_mm<false, true, false><<<mmBlocks, 256, 0, stream>>>(
      aggb, w2b, ro_b2, nullptr, nullptr, amask, outAtom, nullptr, N);
  k_gather<<<U, 32, 0, stream>>>(outH, uindex, outState, U);
}

// Round 3
// 360.330 us; speedup vs baseline: 4.4517x; 1.4559x over previous
//
#include <hip/hip_runtime.h>

#define D 128

typedef __attribute__((ext_vector_type(8))) short bf16x8;
typedef __attribute__((ext_vector_type(4))) float f32x4;

__device__ __forceinline__ ushort f2b(float f) {
  union { float f; unsigned u; } a; a.f = f;
  unsigned u = a.u;
  return (ushort)((u + 0x7fffu + ((u >> 16) & 1u)) >> 16);  // RNE
}
__device__ __forceinline__ float b2f_lo(unsigned v) {
  union { unsigned u; float f; } a; a.u = v << 16; return a.f;
}
__device__ __forceinline__ float b2f_hi(unsigned v) {
  union { unsigned u; float f; } a; a.u = v & 0xffff0000u; return a.f;
}

// ---------- x -> bf16 padded (4 elems/thread) ----------
__global__ void k_cast_pad(const float* __restrict__ s, ushort* __restrict__ d, int n4, int np4) {
  int i = blockIdx.x * blockDim.x + threadIdx.x;
  if (i >= np4) return;
  uint2 pk;
  if (i < n4) {
    float4 v = *(const float4*)&s[i * 4];
    pk.x = (unsigned)f2b(v.x) | ((unsigned)f2b(v.y) << 16);
    pk.y = (unsigned)f2b(v.z) | ((unsigned)f2b(v.w) << 16);
  } else {
    pk = make_uint2(0u, 0u);
  }
  *(uint2*)&d[i * 4] = pk;
}

// ---------- all weights -> bf16, one launch (segmented) ----------
__global__ void k_castw(const float* __restrict__ wl, const float* __restrict__ wr,
                        const float* __restrict__ w1, const float* __restrict__ w2,
                        ushort* __restrict__ dst, int LDD) {
  int i = blockIdx.x * blockDim.x + threadIdx.x;
  int total = 2 * LDD + 2 * D * D;
  if (i >= total) return;
  float v;
  if (i < LDD) v = wl[i];
  else if (i < 2 * LDD) v = wr[i - LDD];
  else if (i < 2 * LDD + D * D) v = w1[i - 2 * LDD];
  else v = w2[i - 2 * LDD - D * D];
  dst[i] = f2b(v);
}

// ---------- CSR build ----------
__global__ void k_hist(const int* __restrict__ dstI, int* __restrict__ cnt, int E) {
  int e = blockIdx.x * blockDim.x + threadIdx.x;
  if (e < E) atomicAdd(&cnt[dstI[e]], 1);
}
__global__ void k_scan1(const int* __restrict__ cnt, int* __restrict__ off,
                        int* __restrict__ bsum, int n) {
  __shared__ int sd[256];
  int t = threadIdx.x;
  int i = blockIdx.x * 256 + t;
  int x = (i < n) ? cnt[i] : 0;
  sd[t] = x;
  __syncthreads();
  for (int s = 1; s < 256; s <<= 1) {
    int v = (t >= s) ? sd[t - s] : 0;
    __syncthreads();
    sd[t] += v;
    __syncthreads();
  }
  if (i < n) off[i] = sd[t] - x;
  if (t == 255) bsum[blockIdx.x] = sd[255];
}
__global__ void k_scan2(const int* __restrict__ bsum, int* __restrict__ boff, int nb) {
  __shared__ int sd[256];
  int t = threadIdx.x;
  int x = (t < nb) ? bsum[t] : 0;
  sd[t] = x;
  __syncthreads();
  for (int s = 1; s < 256; s <<= 1) {
    int v = (t >= s) ? sd[t - s] : 0;
    __syncthreads();
    sd[t] += v;
    __syncthreads();
  }
  if (t < nb) boff[t] = sd[t] - x;
}
__global__ void k_scan3(int* __restrict__ off, const int* __restrict__ boff,
                        int* __restrict__ cursor, int n) {
  int i = blockIdx.x * blockDim.x + threadIdx.x;
  if (i < n) {
    int v = off[i] + boff[i >> 8];
    off[i] = v;
    cursor[i] = v;
  }
}
__global__ void k_fill(const int* __restrict__ srcI, const int* __restrict__ dstI,
                       int* __restrict__ cursor, int* __restrict__ eidx, int E) {
  int e = blockIdx.x * blockDim.x + threadIdx.x;
  if (e < E) {
    int p = atomicAdd(&cursor[dstI[e]], 1);
    eidx[p] = srcI[e];
  }
}

// ---------- neighbor-mean: 16 lanes per node, dwordx4 loads (4 nodes/wave) ----------
__global__ void k_agg(const ushort* __restrict__ hb, const int* __restrict__ off,
                      const int* __restrict__ eidx, ushort* __restrict__ aggb,
                      int N, int Np, int E) {
  int g = (int)(blockIdx.x * (blockDim.x >> 4) + (threadIdx.x >> 4));  // node
  int sub = threadIdx.x & 15;  // 8-feature chunk (16B)
  if (g >= Np) return;
  ushort* dst = &aggb[(size_t)g * D + sub * 8];
  if (g >= N) { *(uint4*)dst = make_uint4(0u, 0u, 0u, 0u); return; }
  int start = off[g];
  int end = (g == N - 1) ? E : off[g + 1];
  float s0 = 0.f, s1 = 0.f, s2 = 0.f, s3 = 0.f, s4 = 0.f, s5 = 0.f, s6 = 0.f, s7 = 0.f;
#pragma unroll 4
  for (int e = start; e < end; ++e) {
    int sn = eidx[e];
    uint4 v = *(const uint4*)&hb[(size_t)sn * D + sub * 8];
    s0 += b2f_lo(v.x); s1 += b2f_hi(v.x);
    s2 += b2f_lo(v.y); s3 += b2f_hi(v.y);
    s4 += b2f_lo(v.z); s5 += b2f_hi(v.z);
    s6 += b2f_lo(v.w); s7 += b2f_hi(v.w);
  }
  float inv = (end > start) ? 1.0f / (float)(end - start) : 0.0f;
  uint4 o;
  o.x = (unsigned)f2b(s0 * inv) | ((unsigned)f2b(s1 * inv) << 16);
  o.y = (unsigned)f2b(s2 * inv) | ((unsigned)f2b(s3 * inv) << 16);
  o.z = (unsigned)f2b(s4 * inv) | ((unsigned)f2b(s5 * inv) << 16);
  o.w = (unsigned)f2b(s6 * inv) | ((unsigned)f2b(s7 * inv) << 16);
  *(uint4*)dst = o;
}

// ---------- MFMA GEMM: out[i][j] = sum_k A1[i][k]*W1[j][k] (+A2*W2) + bias[j]
// 128x128 block, 4 waves 2x2, mfma_f32_16x16x32_bf16, fused column stats.
// OUTBF16: write bf16 (pre-BN buffer). else fp32 (final atom output).
template <bool DUAL, bool MASK, bool STATS, bool OUTBF16>
__global__ __launch_bounds__(256) void k_mm(
    const ushort* __restrict__ A1, const ushort* __restrict__ W1,
    const float* __restrict__ bias,
    const ushort* __restrict__ A2, const ushort* __restrict__ W2,
    const float* __restrict__ mask,
    void* __restrict__ outv, float* __restrict__ sums, int N) {
  __shared__ float ls[2 * D];
  int t = threadIdx.x;
  int lane = t & 63;
  int wid = t >> 6;
  int wr = wid >> 1, wc = wid & 1;
  int r0 = blockIdx.x * 128 + wr * 64;
  int c0 = wc * 64;
  int lr = lane & 15;
  int lk = (lane >> 4) * 8;

  f32x4 acc[4][4];
#pragma unroll
  for (int i = 0; i < 4; ++i)
#pragma unroll
    for (int j = 0; j < 4; ++j) acc[i][j] = (f32x4){0.f, 0.f, 0.f, 0.f};

#pragma unroll
  for (int ks = 0; ks < 4; ++ks) {
    int kb = ks * 32 + lk;
    bf16x8 a1[4], a2[4];
#pragma unroll
    for (int rt = 0; rt < 4; ++rt) {
      a1[rt] = *(const bf16x8*)&A1[(size_t)(r0 + rt * 16 + lr) * D + kb];
      if (DUAL) a2[rt] = *(const bf16x8*)&A2[(size_t)(r0 + rt * 16 + lr) * D + kb];
    }
#pragma unroll
    for (int jt = 0; jt < 4; ++jt) {
      bf16x8 b1 = *(const bf16x8*)&W1[(size_t)(c0 + jt * 16 + lr) * D + kb];
#pragma unroll
      for (int rt = 0; rt < 4; ++rt)
        acc[rt][jt] = __builtin_amdgcn_mfma_f32_16x16x32_bf16(a1[rt], b1, acc[rt][jt], 0, 0, 0);
      if (DUAL) {
        bf16x8 b2 = *(const bf16x8*)&W2[(size_t)(c0 + jt * 16 + lr) * D + kb];
#pragma unroll
        for (int rt = 0; rt < 4; ++rt)
          acc[rt][jt] = __builtin_amdgcn_mfma_f32_16x16x32_bf16(a2[rt], b2, acc[rt][jt], 0, 0, 0);
      }
    }
  }

  if (STATS) {
    if (t < 2 * D) ls[t] = 0.f;
    __syncthreads();
  }

  int crow = (lane >> 4) * 4;
  float s1v[4], s2v[4];
#pragma unroll
  for (int jt = 0; jt < 4; ++jt) { s1v[jt] = 0.f; s2v[jt] = 0.f; }

  float* outf = (float*)outv;
  ushort* outb = (ushort*)outv;
#pragma unroll
  for (int rt = 0; rt < 4; ++rt) {
    int rbase = r0 + rt * 16 + crow;
#pragma unroll
    for (int jt = 0; jt < 4; ++jt) {
      int col = c0 + jt * 16 + lr;
      float bv = bias[col];
#pragma unroll
      for (int rg = 0; rg < 4; ++rg) {
        int row = rbase + rg;
        if (row < N) {
          float v = acc[rt][jt][rg] + bv;
          if (MASK) v *= mask[row];
          if (OUTBF16) outb[(size_t)row * D + col] = f2b(v);
          else outf[(size_t)row * D + col] = v;
          if (STATS) { s1v[jt] += v; s2v[jt] += v * v; }
        }
      }
    }
  }

  if (STATS) {
#pragma unroll
    for (int jt = 0; jt < 4; ++jt) {
      float a = s1v[jt], b = s2v[jt];
      a += __shfl_xor(a, 16, 64); a += __shfl_xor(a, 32, 64);
      b += __shfl_xor(b, 16, 64); b += __shfl_xor(b, 32, 64);
      if (lane < 16) {
        int col = c0 + jt * 16 + lane;
        atomicAdd(&ls[col], a);
        atomicAdd(&ls[D + col], b);
      }
    }
    __syncthreads();
    if (t < 2 * D) atomicAdd(&sums[t], ls[t]);
  }
}

// ---------- BN + ReLU from bf16 pre; writes bf16 next-activation, opt fp32 ----------
template <bool F32OUT>
__global__ void k_bnrelu(const ushort* __restrict__ pre, const float* __restrict__ sums,
                         const float* __restrict__ gamma, const float* __restrict__ beta,
                         float* __restrict__ fout, ushort* __restrict__ bout,
                         int N, int Np, float invN) {
  int i4 = blockIdx.x * blockDim.x + threadIdx.x;
  if (i4 >= Np * (D / 4)) return;
  int row = i4 >> 5;
  int c4 = (i4 & 31) * 4;
  uint2 pk;
  if (row < N) {
    uint2 pv = *(const uint2*)&pre[(size_t)row * D + c4];
    float4 v = make_float4(b2f_lo(pv.x), b2f_hi(pv.x), b2f_lo(pv.y), b2f_hi(pv.y));
    float4 s = *(const float4*)&sums[c4];
    float4 q = *(const float4*)&sums[D + c4];
    float4 g = *(const float4*)&gamma[c4];
    float4 b = *(const float4*)&beta[c4];
    float mu, var, sc, sh;
    mu = s.x * invN; var = fmaxf(q.x * invN - mu * mu, 0.f);
    sc = g.x * rsqrtf(var + 1e-5f); sh = b.x - mu * sc;
    v.x = fmaxf(fmaf(v.x, sc, sh), 0.f);
    mu = s.y * invN; var = fmaxf(q.y * invN - mu * mu, 0.f);
    sc = g.y * rsqrtf(var + 1e-5f); sh = b.y - mu * sc;
    v.y = fmaxf(fmaf(v.y, sc, sh), 0.f);
    mu = s.z * invN; var = fmaxf(q.z * invN - mu * mu, 0.f);
    sc = g.z * rsqrtf(var + 1e-5f); sh = b.z - mu * sc;
    v.z = fmaxf(fmaf(v.z, sc, sh), 0.f);
    mu = s.w * invN; var = fmaxf(q.w * invN - mu * mu, 0.f);
    sc = g.w * rsqrtf(var + 1e-5f); sh = b.w - mu * sc;
    v.w = fmaxf(fmaf(v.w, sc, sh), 0.f);
    if (F32OUT) *(float4*)&fout[(size_t)row * D + c4] = v;
    pk.x = (unsigned)f2b(v.x) | ((unsigned)f2b(v.y) << 16);
    pk.y = (unsigned)f2b(v.z) | ((unsigned)f2b(v.w) << 16);
  } else {
    pk = make_uint2(0u, 0u);
  }
  *(uint2*)&bout[(size_t)row * D + c4] = pk;
}

// ---------- state gather ----------
__global__ void k_gather(const float* __restrict__ h, const int* __restrict__ uidx,
                         float* __restrict__ outp, int U) {
  int u = blockIdx.x;
  int t = threadIdx.x;  // 32 threads
  int s = uidx[u];
  *(float4*)&outp[(size_t)u * D + t * 4] = *(const float4*)&h[(size_t)s * D + t * 4];
}

extern "C" void kernel_launch(void* const* d_in, const int* in_sizes, int n_in,
                              void* d_out, int out_size, void* d_ws, size_t ws_size,
                              hipStream_t stream) {
  const float* x        = (const float*)d_in[0];
  const int*   edge     = (const int*)d_in[1];
  const float* amask    = (const float*)d_in[2];
  const int*   uindex   = (const int*)d_in[3];
  const float* lin_l_w  = (const float*)d_in[4];
  const float* lin_l_b  = (const float*)d_in[5];
  const float* lin_r_w  = (const float*)d_in[6];
  const float* bn_gamma = (const float*)d_in[7];
  const float* bn_beta  = (const float*)d_in[8];
  const float* ro_w1    = (const float*)d_in[9];
  const float* ro_b1    = (const float*)d_in[10];
  const float* ro_bng   = (const float*)d_in[11];
  const float* ro_bnb   = (const float*)d_in[12];
  const float* ro_w2    = (const float*)d_in[13];
  const float* ro_b2    = (const float*)d_in[14];

  const int N = in_sizes[0] / D;
  const int E = in_sizes[1] / 2;
  const int U = in_sizes[3];
  const int L = in_sizes[4] / (D * D);
  const int Np = ((N + 127) / 128) * 128;
  const int LDD = L * D * D;

  const int* srcI = edge;
  const int* dstI = edge + E;

  float* outH     = (float*)d_out;               // [N][D]
  float* outAtom  = outH + (size_t)N * D;        // [N][D]
  float* outState = outAtom + (size_t)N * D;     // [U][D]

  // workspace carve
  char* w = (char*)d_ws;
  ushort* hb   = (ushort*)w; w += (size_t)Np * D * 2;
  ushort* aggb = (ushort*)w; w += (size_t)Np * D * 2;
  ushort* pre  = (ushort*)w; w += (size_t)Np * D * 2;
  ushort* wall = (ushort*)w; w += (size_t)(2 * LDD + 2 * D * D) * 2;
  float*  sums = (float*)w;  w += 4 * 2 * D * 4;   // 4 stats passes
  int* off    = (int*)w;     w += (size_t)(N + 1) * 4;
  int* cursor = (int*)w;     w += (size_t)N * 4;
  int* bsum   = (int*)w;     w += 1024;
  int* boff   = (int*)w;     w += 1024;
  int* eidx   = (int*)w;     w += (size_t)E * 4;

  ushort* wlb = wall;
  ushort* wrb = wlb + (size_t)LDD;
  ushort* w1b = wrb + (size_t)LDD;
  ushort* w2b = w1b + (size_t)D * D;

  // 1) casts + zero stats
  k_cast_pad<<<(Np * D / 4 + 255) / 256, 256, 0, stream>>>(x, hb, N * D / 4, Np * D / 4);
  k_castw<<<(2 * LDD + 2 * D * D + 255) / 256, 256, 0, stream>>>(lin_l_w, lin_r_w, ro_w1, ro_w2, wall, LDD);
  hipMemsetAsync(sums, 0, 4 * 2 * D * 4, stream);

  // 2) CSR build (cursor doubles as cnt)
  hipMemsetAsync(cursor, 0, (size_t)N * 4, stream);
  int nbE = (E + 255) / 256;
  int nbN = (N + 255) / 256;
  k_hist<<<nbE, 256, 0, stream>>>(dstI, cursor, E);
  k_scan1<<<nbN, 256, 0, stream>>>(cursor, off, bsum, N);
  k_scan2<<<1, 256, 0, stream>>>(bsum, boff, nbN);
  k_scan3<<<nbN, 256, 0, stream>>>(off, boff, cursor, N);
  k_fill<<<nbE, 256, 0, stream>>>(srcI, dstI, cursor, eidx, E);

  const int mmBlocks = Np / 128;
  const int aggBlocks = Np / 16;                 // 16 nodes per 256-thr block
  const int bnBlocks = (Np * (D / 4) + 255) / 256;
  const float invN = 1.0f / (float)N;

  // 3) layers
  for (int l = 0; l < L; ++l) {
    float* lsums = sums + (size_t)l * 2 * D;
    k_agg<<<aggBlocks, 256, 0, stream>>>(hb, off, eidx, aggb, N, Np, E);
    k_mm<true, false, true, true><<<mmBlocks, 256, 0, stream>>>(
        aggb, wlb + (size_t)l * D * D, lin_l_b + (size_t)l * D,
        hb, wrb + (size_t)l * D * D, nullptr, pre, lsums, N);
    if (l == L - 1)
      k_bnrelu<true><<<bnBlocks, 256, 0, stream>>>(pre, lsums, bn_gamma + (size_t)l * D,
                                                   bn_beta + (size_t)l * D, outH, hb, N, Np, invN);
    else
      k_bnrelu<false><<<bnBlocks, 256, 0, stream>>>(pre, lsums, bn_gamma + (size_t)l * D,
                                                    bn_beta + (size_t)l * D, nullptr, hb, N, Np, invN);
  }

  // 4) readout
  float* rsums = sums + (size_t)L * 2 * D;
  k_mm<false, false, true, true><<<mmBlocks, 256, 0, stream>>>(
      hb, w1b, ro_b1, nullptr, nullptr, nullptr, pre, rsums, N);
  k_bnrelu<false><<<bnBlocks, 256, 0, stream>>>(pre, rsums, ro_bng, ro_bnb, nullptr, aggb, N, Np, invN);
  k_mm<false, true, false, false><<<mmBlocks, 256, 0, stream>>>(
      aggb, w2b, ro_b2, nullptr, nullptr, amask, outAtom, nullptr, N);
  k_gather<<<U, 32, 0, stream>>>(outH, uindex, outState, U);
}

// Round 5
// 328.685 us; speedup vs baseline: 4.8803x; 1.0963x over previous
//
#include <hip/hip_runtime.h>

#define D 128
#define LDA 136  // LDS agg row stride in ushorts: 272B, 16B-aligned, 2-way-bank-free

typedef __attribute__((ext_vector_type(8))) short bf16x8;
typedef __attribute__((ext_vector_type(4))) float f32x4;

__device__ __forceinline__ ushort f2b(float f) {
  union { float f; unsigned u; } a; a.f = f;
  unsigned u = a.u;
  return (ushort)((u + 0x7fffu + ((u >> 16) & 1u)) >> 16);  // RNE
}
__device__ __forceinline__ float b2f_lo(unsigned v) {
  union { unsigned u; float f; } a; a.u = v << 16; return a.f;
}
__device__ __forceinline__ float b2f_hi(unsigned v) {
  union { unsigned u; float f; } a; a.u = v & 0xffff0000u; return a.f;
}

// ---------- x -> bf16 padded ----------
__global__ void k_cast_pad(const float* __restrict__ s, ushort* __restrict__ d, int n4, int np4) {
  int i = blockIdx.x * blockDim.x + threadIdx.x;
  if (i >= np4) return;
  uint2 pk;
  if (i < n4) {
    float4 v = *(const float4*)&s[i * 4];
    pk.x = (unsigned)f2b(v.x) | ((unsigned)f2b(v.y) << 16);
    pk.y = (unsigned)f2b(v.z) | ((unsigned)f2b(v.w) << 16);
  } else {
    pk = make_uint2(0u, 0u);
  }
  *(uint2*)&d[i * 4] = pk;
}

// ---------- all weights -> bf16 ----------
__global__ void k_castw(const float* __restrict__ wl, const float* __restrict__ wr,
                        const float* __restrict__ w1, const float* __restrict__ w2,
                        ushort* __restrict__ dst, int LDD) {
  int i = blockIdx.x * blockDim.x + threadIdx.x;
  int total = 2 * LDD + 2 * D * D;
  if (i >= total) return;
  float v;
  if (i < LDD) v = wl[i];
  else if (i < 2 * LDD) v = wr[i - LDD];
  else if (i < 2 * LDD + D * D) v = w1[i - 2 * LDD];
  else v = w2[i - 2 * LDD - D * D];
  dst[i] = f2b(v);
}

// ---------- CSR build: hist with rank recording ----------
__global__ void k_histrank(const int* __restrict__ dstI, int* __restrict__ cnt,
                           int* __restrict__ rankdst, int E) {
  int e = blockIdx.x * blockDim.x + threadIdx.x;
  if (e < E) {
    int d = dstI[e];
    int r = atomicAdd(&cnt[d], 1);
    rankdst[e] = (r << 16) | d;
  }
}
__global__ void k_scan1(const int* __restrict__ cnt, int* __restrict__ off,
                        int* __restrict__ bsum, int n) {
  __shared__ int sd[256];
  int t = threadIdx.x;
  int i = blockIdx.x * 256 + t;
  int x = (i < n) ? cnt[i] : 0;
  sd[t] = x;
  __syncthreads();
  for (int s = 1; s < 256; s <<= 1) {
    int v = (t >= s) ? sd[t - s] : 0;
    __syncthreads();
    sd[t] += v;
    __syncthreads();
  }
  if (i < n) off[i] = sd[t] - x;
  if (t == 255) bsum[blockIdx.x] = sd[255];
}
__global__ void k_scan2(const int* __restrict__ bsum, int* __restrict__ boff, int nb) {
  __shared__ int sd[256];
  int t = threadIdx.x;
  int x = (t < nb) ? bsum[t] : 0;
  sd[t] = x;
  __syncthreads();
  for (int s = 1; s < 256; s <<= 1) {
    int v = (t >= s) ? sd[t - s] : 0;
    __syncthreads();
    sd[t] += v;
    __syncthreads();
  }
  if (t < nb) boff[t] = sd[t] - x;
}
__global__ void k_scan3(int* __restrict__ off, const int* __restrict__ boff, int n) {
  int i = blockIdx.x * blockDim.x + threadIdx.x;
  if (i < n) off[i] += boff[i >> 8];
}
// non-atomic scatter fill
__global__ void k_fill(const int* __restrict__ srcI, const int* __restrict__ rankdst,
                       const int* __restrict__ off, int* __restrict__ eidx, int E) {
  int e = blockIdx.x * blockDim.x + threadIdx.x;
  if (e < E) {
    int rd = rankdst[e];
    int d = rd & 0xFFFF;
    eidx[off[d] + (rd >> 16)] = srcI[e];
  }
}

#define ACC8(V, B)                                        \
  a[B + 0] += b2f_lo(V.x); a[B + 1] += b2f_hi(V.x);       \
  a[B + 2] += b2f_lo(V.y); a[B + 3] += b2f_hi(V.y);       \
  a[B + 4] += b2f_lo(V.z); a[B + 5] += b2f_hi(V.z);       \
  a[B + 6] += b2f_lo(V.w); a[B + 7] += b2f_hi(V.w);

// ---------- fused: [gather-mean -> LDS] + dual GEMM + bias + col-stats -> pre bf16, sums
// 512 threads, 128x128 tile, 8 waves (4 row x 2 col), mfma_f32_16x16x32_bf16.
// AGG=false: single GEMM on hin (readout z path).
template <bool AGG>
__global__ __launch_bounds__(512) void k_fused(
    const ushort* __restrict__ hin, const ushort* __restrict__ Wl,
    const ushort* __restrict__ Wr, const float* __restrict__ bias,
    const int* __restrict__ off, const int* __restrict__ eidx,
    ushort* __restrict__ pre, float* __restrict__ sums, int N, int E) {
  __shared__ ushort aggS[128 * LDA];
  __shared__ float ls[2 * D];
  int t = threadIdx.x;
  int r0 = blockIdx.x * 128;

  if (t < 2 * D) ls[t] = 0.f;

  if (AGG) {
    // gather-mean into LDS: 4 threads per row, 32 features (64B) each
    int lrow = t >> 2;
    int row = r0 + lrow;
    int part = (t & 3) << 5;
    float a[32];
#pragma unroll
    for (int i = 0; i < 32; ++i) a[i] = 0.f;
    int start = 0, end = 0;
    if (row < N) { start = off[row]; end = (row == N - 1) ? E : off[row + 1]; }
    const ushort* hbase = hin + part;
#pragma unroll 2
    for (int e = start; e < end; ++e) {
      int sn = eidx[e];
      const uint4* p = (const uint4*)(hbase + (size_t)sn * D);
      uint4 v0 = p[0], v1 = p[1], v2 = p[2], v3 = p[3];
      ACC8(v0, 0) ACC8(v1, 8) ACC8(v2, 16) ACC8(v3, 24)
    }
    float inv = (end > start) ? 1.0f / (float)(end - start) : 0.f;
    unsigned o[16];
#pragma unroll
    for (int i = 0; i < 16; ++i)
      o[i] = (unsigned)f2b(a[2 * i] * inv) | ((unsigned)f2b(a[2 * i + 1] * inv) << 16);
    uint4* dst = (uint4*)&aggS[lrow * LDA + part];
    dst[0] = make_uint4(o[0], o[1], o[2], o[3]);
    dst[1] = make_uint4(o[4], o[5], o[6], o[7]);
    dst[2] = make_uint4(o[8], o[9], o[10], o[11]);
    dst[3] = make_uint4(o[12], o[13], o[14], o[15]);
  }
  __syncthreads();

  // MFMA phase
  int lane = t & 63;
  int wid = t >> 6;
  int wr = wid >> 1, wc = wid & 1;
  int rw = wr * 32, cw = wc * 64;
  int lr = lane & 15, lk = (lane >> 4) * 8;

  f32x4 acc[2][4];
#pragma unroll
  for (int i = 0; i < 2; ++i)
#pragma unroll
    for (int j = 0; j < 4; ++j) acc[i][j] = (f32x4){0.f, 0.f, 0.f, 0.f};

#pragma unroll
  for (int ks = 0; ks < 4; ++ks) {
    int kb = ks * 32 + lk;
    bf16x8 aA[2], aB[2];
#pragma unroll
    for (int rt = 0; rt < 2; ++rt) {
      if (AGG) {
        aA[rt] = *(const bf16x8*)&aggS[(rw + rt * 16 + lr) * LDA + kb];
        aB[rt] = *(const bf16x8*)&hin[(size_t)(r0 + rw + rt * 16 + lr) * D + kb];
      } else {
        aA[rt] = *(const bf16x8*)&hin[(size_t)(r0 + rw + rt * 16 + lr) * D + kb];
      }
    }
#pragma unroll
    for (int jt = 0; jt < 4; ++jt) {
      bf16x8 b1 = *(const bf16x8*)&Wl[(size_t)(cw + jt * 16 + lr) * D + kb];
      acc[0][jt] = __builtin_amdgcn_mfma_f32_16x16x32_bf16(aA[0], b1, acc[0][jt], 0, 0, 0);
      acc[1][jt] = __builtin_amdgcn_mfma_f32_16x16x32_bf16(aA[1], b1, acc[1][jt], 0, 0, 0);
      if (AGG) {
        bf16x8 b2 = *(const bf16x8*)&Wr[(size_t)(cw + jt * 16 + lr) * D + kb];
        acc[0][jt] = __builtin_amdgcn_mfma_f32_16x16x32_bf16(aB[0], b2, acc[0][jt], 0, 0, 0);
        acc[1][jt] = __builtin_amdgcn_mfma_f32_16x16x32_bf16(aB[1], b2, acc[1][jt], 0, 0, 0);
      }
    }
  }

  // bias + write pre (bf16) + column stats
  int crow = (lane >> 4) * 4;
#pragma unroll
  for (int jt = 0; jt < 4; ++jt) {
    int col = cw + jt * 16 + lr;
    float bv = bias[col];
    float s1 = 0.f, s2 = 0.f;
#pragma unroll
    for (int rt = 0; rt < 2; ++rt) {
      int rbase = r0 + rw + rt * 16 + crow;
#pragma unroll
      for (int rg = 0; rg < 4; ++rg) {
        int row = rbase + rg;
        if (row < N) {
          float v = acc[rt][jt][rg] + bv;
          pre[(size_t)row * D + col] = f2b(v);
          s1 += v; s2 += v * v;
        }
      }
    }
    s1 += __shfl_xor(s1, 16, 64); s1 += __shfl_xor(s1, 32, 64);
    s2 += __shfl_xor(s2, 16, 64); s2 += __shfl_xor(s2, 32, 64);
    if (lane < 16) {
      atomicAdd(&ls[cw + jt * 16 + lane], s1);
      atomicAdd(&ls[D + cw + jt * 16 + lane], s2);
    }
  }
  __syncthreads();
  if (t < 2 * D) atomicAdd(&sums[t], ls[t]);
}

// ---------- BN + ReLU from bf16 pre; writes bf16 next-activation, opt fp32 ----------
template <bool F32OUT>
__global__ void k_bnrelu(const ushort* __restrict__ pre, const float* __restrict__ sums,
                         const float* __restrict__ gamma, const float* __restrict__ beta,
                         float* __restrict__ fout, ushort* __restrict__ bout,
                         int N, int Np, float invN) {
  int i4 = blockIdx.x * blockDim.x + threadIdx.x;
  if (i4 >= Np * (D / 4)) return;
  int row = i4 >> 5;
  int c4 = (i4 & 31) * 4;
  uint2 pk;
  if (row < N) {
    uint2 pv = *(const uint2*)&pre[(size_t)row * D + c4];
    float4 v = make_float4(b2f_lo(pv.x), b2f_hi(pv.x), b2f_lo(pv.y), b2f_hi(pv.y));
    float4 s = *(const float4*)&sums[c4];
    float4 q = *(const float4*)&sums[D + c4];
    float4 g = *(const float4*)&gamma[c4];
    float4 b = *(const float4*)&beta[c4];
    float mu, var, sc, sh;
    mu = s.x * invN; var = fmaxf(q.x * invN - mu * mu, 0.f);
    sc = g.x * rsqrtf(var + 1e-5f); sh = b.x - mu * sc;
    v.x = fmaxf(fmaf(v.x, sc, sh), 0.f);
    mu = s.y * invN; var = fmaxf(q.y * invN - mu * mu, 0.f);
    sc = g.y * rsqrtf(var + 1e-5f); sh = b.y - mu * sc;
    v.y = fmaxf(fmaf(v.y, sc, sh), 0.f);
    mu = s.z * invN; var = fmaxf(q.z * invN - mu * mu, 0.f);
    sc = g.z * rsqrtf(var + 1e-5f); sh = b.z - mu * sc;
    v.z = fmaxf(fmaf(v.z, sc, sh), 0.f);
    mu = s.w * invN; var = fmaxf(q.w * invN - mu * mu, 0.f);
    sc = g.w * rsqrtf(var + 1e-5f); sh = b.w - mu * sc;
    v.w = fmaxf(fmaf(v.w, sc, sh), 0.f);
    if (F32OUT) *(float4*)&fout[(size_t)row * D + c4] = v;
    pk.x = (unsigned)f2b(v.x) | ((unsigned)f2b(v.y) << 16);
    pk.y = (unsigned)f2b(v.z) | ((unsigned)f2b(v.w) << 16);
  } else {
    pk = make_uint2(0u, 0u);
  }
  *(uint2*)&bout[(size_t)row * D + c4] = pk;
}

// ---------- final GEMM: atom = (z @ W2.T + b2) * mask, fp32 out ----------
__global__ __launch_bounds__(256) void k_mmfin(
    const ushort* __restrict__ A, const ushort* __restrict__ W,
    const float* __restrict__ bias, const float* __restrict__ mask,
    float* __restrict__ out, int N) {
  int t = threadIdx.x;
  int lane = t & 63;
  int wid = t >> 6;
  int wr = wid >> 1, wc = wid & 1;
  int r0 = blockIdx.x * 128 + wr * 64;
  int c0 = wc * 64;
  int lr = lane & 15, lk = (lane >> 4) * 8;

  f32x4 acc[4][4];
#pragma unroll
  for (int i = 0; i < 4; ++i)
#pragma unroll
    for (int j = 0; j < 4; ++j) acc[i][j] = (f32x4){0.f, 0.f, 0.f, 0.f};

#pragma unroll
  for (int ks = 0; ks < 4; ++ks) {
    int kb = ks * 32 + lk;
    bf16x8 a1[4];
#pragma unroll
    for (int rt = 0; rt < 4; ++rt)
      a1[rt] = *(const bf16x8*)&A[(size_t)(r0 + rt * 16 + lr) * D + kb];
#pragma unroll
    for (int jt = 0; jt < 4; ++jt) {
      bf16x8 b1 = *(const bf16x8*)&W[(size_t)(c0 + jt * 16 + lr) * D + kb];
#pragma unroll
      for (int rt = 0; rt < 4; ++rt)
        acc[rt][jt] = __builtin_amdgcn_mfma_f32_16x16x32_bf16(a1[rt], b1, acc[rt][jt], 0, 0, 0);
    }
  }

  int crow = (lane >> 4) * 4;
#pragma unroll
  for (int rt = 0; rt < 4; ++rt) {
    int rbase = r0 + rt * 16 + crow;
#pragma unroll
    for (int jt = 0; jt < 4; ++jt) {
      int col = c0 + jt * 16 + lr;
      float bv = bias[col];
#pragma unroll
      for (int rg = 0; rg < 4; ++rg) {
        int row = rbase + rg;
        if (row < N) {
          float m = mask[row];
          out[(size_t)row * D + col] = (acc[rt][jt][rg] + bv) * m;
        }
      }
    }
  }
}

// ---------- state gather ----------
__global__ void k_gather(const float* __restrict__ h, const int* __restrict__ uidx,
                         float* __restrict__ outp, int U) {
  int u = blockIdx.x;
  int t = threadIdx.x;  // 32 threads
  int s = uidx[u];
  *(float4*)&outp[(size_t)u * D + t * 4] = *(const float4*)&h[(size_t)s * D + t * 4];
}

extern "C" void kernel_launch(void* const* d_in, const int* in_sizes, int n_in,
                              void* d_out, int out_size, void* d_ws, size_t ws_size,
                              hipStream_t stream) {
  const float* x        = (const float*)d_in[0];
  const int*   edge     = (const int*)d_in[1];
  const float* amask    = (const float*)d_in[2];
  const int*   uindex   = (const int*)d_in[3];
  const float* lin_l_w  = (const float*)d_in[4];
  const float* lin_l_b  = (const float*)d_in[5];
  const float* lin_r_w  = (const float*)d_in[6];
  const float* bn_gamma = (const float*)d_in[7];
  const float* bn_beta  = (const float*)d_in[8];
  const float* ro_w1    = (const float*)d_in[9];
  const float* ro_b1    = (const float*)d_in[10];
  const float* ro_bng   = (const float*)d_in[11];
  const float* ro_bnb   = (const float*)d_in[12];
  const float* ro_w2    = (const float*)d_in[13];
  const float* ro_b2    = (const float*)d_in[14];

  const int N = in_sizes[0] / D;
  const int E = in_sizes[1] / 2;
  const int U = in_sizes[3];
  const int L = in_sizes[4] / (D * D);
  const int Np = ((N + 127) / 128) * 128;
  const int LDD = L * D * D;

  const int* srcI = edge;
  const int* dstI = edge + E;

  float* outH     = (float*)d_out;               // [N][D]
  float* outAtom  = outH + (size_t)N * D;        // [N][D]
  float* outState = outAtom + (size_t)N * D;     // [U][D]

  // workspace carve
  char* w = (char*)d_ws;
  ushort* hb   = (ushort*)w; w += (size_t)Np * D * 2;
  ushort* pre  = (ushort*)w; w += (size_t)Np * D * 2;
  ushort* wall = (ushort*)w; w += (size_t)(2 * LDD + 2 * D * D) * 2;
  int*    cnt  = (int*)w;    w += (size_t)N * 4;
  float*  sums = (float*)w;  w += 4 * 2 * D * 4;
  int* off     = (int*)w;    w += (size_t)N * 4;
  int* rankdst = (int*)w;    w += (size_t)E * 4;
  int* eidx    = (int*)w;    w += (size_t)E * 4;
  int* bsum    = (int*)w;    w += 1024;
  int* boff    = (int*)w;    w += 1024;

  ushort* wlb = wall;
  ushort* wrb = wlb + (size_t)LDD;
  ushort* w1b = wrb + (size_t)LDD;
  ushort* w2b = w1b + (size_t)D * D;

  // 1) casts + zero cnt & sums (contiguous)
  k_cast_pad<<<(Np * D / 4 + 255) / 256, 256, 0, stream>>>(x, hb, N * D / 4, Np * D / 4);
  k_castw<<<(2 * LDD + 2 * D * D + 255) / 256, 256, 0, stream>>>(lin_l_w, lin_r_w, ro_w1, ro_w2, wall, LDD);
  hipMemsetAsync(cnt, 0, (size_t)N * 4 + 4 * 2 * D * 4, stream);

  // 2) CSR build (rank-based, no atomic in fill)
  int nbE = (E + 255) / 256;
  int nbN = (N + 255) / 256;
  k_histrank<<<nbE, 256, 0, stream>>>(dstI, cnt, rankdst, E);
  k_scan1<<<nbN, 256, 0, stream>>>(cnt, off, bsum, N);
  k_scan2<<<1, 256, 0, stream>>>(bsum, boff, nbN);
  k_scan3<<<nbN, 256, 0, stream>>>(off, boff, N);
  k_fill<<<nbE, 256, 0, stream>>>(srcI, rankdst, off, eidx, E);

  const int mmBlocks = Np / 128;
  const int bnBlocks = (Np * (D / 4) + 255) / 256;
  const float invN = 1.0f / (float)N;

  // 3) layers (hb updated in place by bnrelu)
  for (int l = 0; l < L; ++l) {
    float* lsums = sums + (size_t)l * 2 * D;
    k_fused<true><<<mmBlocks, 512, 0, stream>>>(
        hb, wlb + (size_t)l * D * D, wrb + (size_t)l * D * D,
        lin_l_b + (size_t)l * D, off, eidx, pre, lsums, N, E);
    if (l == L - 1)
      k_bnrelu<true><<<bnBlocks, 256, 0, stream>>>(pre, lsums, bn_gamma + (size_t)l * D,
                                                   bn_beta + (size_t)l * D, outH, hb, N, Np, invN);
    else
      k_bnrelu<false><<<bnBlocks, 256, 0, stream>>>(pre, lsums, bn_gamma + (size_t)l * D,
                                                    bn_beta + (size_t)l * D, nullptr, hb, N, Np, invN);
  }

  // 4) readout: z = relu(bn(h @ w1.T + b1)); z overwrites hb (h no longer needed in bf16)
  float* rsums = sums + (size_t)L * 2 * D;
  k_fused<false><<<mmBlocks, 512, 0, stream>>>(
      hb, w1b, nullptr, ro_b1, off, eidx, pre, rsums, N, E);
  k_bnrelu<false><<<bnBlocks, 256, 0, stream>>>(pre, rsums, ro_bng, ro_bnb, nullptr, hb, N, Np, invN);
  k_mmfin<<<mmBlocks, 256, 0, stream>>>(hb, w2b, ro_b2, amask, outAtom, N);
  k_gather<<<U, 32, 0, stream>>>(outH, uindex, outState, U);
}